// Round 1
// baseline (357.587 us; speedup 1.0000x reference)
//
#include <hip/hip_runtime.h>

// HemorrhageNet: per-row Poisson-binomial count distribution over 96 probs,
// truncated at 5, binned to severity[5] = {c0, c1+c2, c3+c4, c5, 0}.
//
// B = 1048576 rows, 3 inputs of (B,32) fp32, output (B,5) fp32.
// Memory-bound: ~424 MB traffic -> ~67 us floor at 6.3 TB/s.
//
// Layout strategy:
//  - 1 thread per row, 128 rows / 128 threads per block, 8192 blocks.
//  - Stage all 3 input tiles (48 KB) into LDS via global_load_lds width=16:
//      global pattern: 8 lanes cover one full 128B row-line -> 8 full lines
//      per wave instruction (ideal coalescing).
//      LDS dest is wave-uniform base + lane*16 (HW constraint), which forces
//      an XOR swizzle: logical (row r, col4 c) lives at physical slot c^(r&7).
//  - Compute phase: thread t reads its own row with ds_read_b128 at
//      slot j^(t&7): per 8-lane group slots permute 0..7 -> uniform bank use,
//      same profile as canonical contiguous b128 (conflict-free).
//  - Output staged via LDS -> fully coalesced stores.

#define ROWS_PER_BLOCK 128
#define THREADS 128

__global__ __launch_bounds__(THREADS) void hemorrhage_kernel(
    const float* __restrict__ x1,
    const float* __restrict__ x2,
    const float* __restrict__ x3,
    float* __restrict__ out)
{
    __shared__ float smem[3 * ROWS_PER_BLOCK * 32];  // 48 KB -> 3 blocks/CU

    const int t = threadIdx.x;
    const int l = t & 63;        // lane in wave
    const int w = t >> 6;        // wave id (0..1)
    const long long block_row0 = (long long)blockIdx.x * ROWS_PER_BLOCK;

    const int lrow8 = l >> 3;                 // 0..7: row within wave's 8-row group
    const int lcol  = (l & 7) ^ (lrow8 & 7);  // swizzled col4 this lane fetches

    // ---- stage all three arrays into LDS (async, direct-to-LDS) ----
    const float* srcs[3] = {x1, x2, x3};
#pragma unroll
    for (int a = 0; a < 3; ++a) {
        const float* src = srcs[a];
#pragma unroll
        for (int i = 0; i < 8; ++i) {
            // rows covered this round by this wave: i*16 + w*8 + (0..7)
            const int rlocal = i * 16 + w * 8 + lrow8;
            const float* gptr = src + (block_row0 + rlocal) * 32 + lcol * 4;
            // wave-uniform LDS base; HW writes lane's 16B at base + l*16
            float* lptr = &smem[a * (ROWS_PER_BLOCK * 32) + (i * 16 + w * 8) * 32];
            __builtin_amdgcn_global_load_lds(
                (const __attribute__((address_space(1))) void*)gptr,
                (__attribute__((address_space(3))) void*)lptr,
                16, 0, 0);
        }
    }
    __syncthreads();  // drains vmcnt(0): all LDS tiles resident

    // ---- per-row recurrence over 96 probabilities ----
    float c0 = 1.0f, c1 = 0.0f, c2 = 0.0f, c3 = 0.0f, c4 = 0.0f, c5 = 0.0f;
    const int tswz = t & 7;
#pragma unroll
    for (int a = 0; a < 3; ++a) {
        const float4* rowbase =
            (const float4*)&smem[a * (ROWS_PER_BLOCK * 32) + t * 32];
#pragma unroll
        for (int j = 0; j < 8; ++j) {
            const float4 p4 = rowbase[j ^ tswz];  // ds_read_b128, deswizzled
            const float ps[4] = {p4.x, p4.y, p4.z, p4.w};
#pragma unroll
            for (int k = 0; k < 4; ++k) {
                const float p = ps[k];
                const float q = 1.0f - p;
                // update top-down so each line consumes OLD values
                c5 = fmaf(c4, p, c5);          // saturating bin: c5 += c4*p
                c4 = fmaf(c4, q, c3 * p);
                c3 = fmaf(c3, q, c2 * p);
                c2 = fmaf(c2, q, c1 * p);
                c1 = fmaf(c1, q, c0 * p);
                c0 = c0 * q;
            }
        }
    }

    // ---- stage severity outputs in LDS, then coalesced store ----
    __syncthreads();  // everyone done reading smem before reuse
    smem[t * 5 + 0] = c0;
    smem[t * 5 + 1] = c1 + c2;
    smem[t * 5 + 2] = c3 + c4;
    smem[t * 5 + 3] = c5;
    smem[t * 5 + 4] = 0.0f;   // out is re-poisoned 0xAA: must write the zero col
    __syncthreads();

    float* outb = out + block_row0 * 5;
#pragma unroll
    for (int k = 0; k < 5; ++k) {
        outb[k * THREADS + t] = smem[k * THREADS + t];
    }
}

extern "C" void kernel_launch(void* const* d_in, const int* in_sizes, int n_in,
                              void* d_out, int out_size, void* d_ws, size_t ws_size,
                              hipStream_t stream) {
    const float* x1 = (const float*)d_in[0];
    const float* x2 = (const float*)d_in[1];
    const float* x3 = (const float*)d_in[2];
    float* out = (float*)d_out;

    const int rows = in_sizes[0] / 32;            // 1048576
    const int blocks = rows / ROWS_PER_BLOCK;     // 8192 (exact)
    hemorrhage_kernel<<<blocks, THREADS, 0, stream>>>(x1, x2, x3, out);
}

// Round 2
// 346.642 us; speedup vs baseline: 1.0316x; 1.0316x over previous
//
#include <hip/hip_runtime.h>

// HemorrhageNet: per-row Poisson-binomial count distribution over 96 probs,
// truncated at 5, binned to severity[5] = {c0, c1+c2, c3+c4, c5, 0}.
//
// R2 strategy: the distribution is order-invariant and composable.
//  - 8 lanes per row; each lane loads one float4 from each of x1,x2,x3
//    (fully coalesced: lane i -> base + i*16B, 1 KiB per wave instruction).
//  - Each lane builds the truncated (deg<=5, saturating) distribution of its
//    12 probs: 12 x 6 FMA recurrence.
//  - Butterfly combine over the 8-lane group via __shfl_xor (d=1,2,4):
//    truncated convolution; tail coefficient via mass conservation
//    n5 = 1 - (n0+..+n4)  (each partial distribution sums to exactly 1).
//  - Lanes m<5 of each group store severity directly: 40 active lanes per
//    wave covering 160 contiguous bytes -> well-coalesced.
// No LDS, no barriers -> occupancy limited only by VGPRs (~24+ waves/CU).

#define THREADS 256

__global__ __launch_bounds__(THREADS, 6) void hemorrhage_kernel(
    const float* __restrict__ x1,
    const float* __restrict__ x2,
    const float* __restrict__ x3,
    float* __restrict__ out)
{
    const int t = threadIdx.x;
    const int m = t & 7;                                  // slot within row group
    const int row = blockIdx.x * (THREADS / 8) + (t >> 3);
    const size_t base = (size_t)row * 32 + (size_t)m * 4;

    // ---- coalesced loads: 3 independent float4s ----
    const float4 p1 = *(const float4*)(x1 + base);
    const float4 p2 = *(const float4*)(x2 + base);
    const float4 p3 = *(const float4*)(x3 + base);

    // ---- local truncated distribution over this lane's 12 probs ----
    float a0 = 1.0f, a1 = 0.0f, a2 = 0.0f, a3 = 0.0f, a4 = 0.0f, a5 = 0.0f;

#define STEP(P)                          \
    do {                                 \
        const float p_ = (P);            \
        const float q_ = 1.0f - p_;      \
        a5 = fmaf(a4, p_, a5);           \
        a4 = fmaf(a4, q_, a3 * p_);      \
        a3 = fmaf(a3, q_, a2 * p_);      \
        a2 = fmaf(a2, q_, a1 * p_);      \
        a1 = fmaf(a1, q_, a0 * p_);      \
        a0 = a0 * q_;                    \
    } while (0)

    STEP(p1.x); STEP(p1.y); STEP(p1.z); STEP(p1.w);
    STEP(p2.x); STEP(p2.y); STEP(p2.z); STEP(p2.w);
    STEP(p3.x); STEP(p3.y); STEP(p3.z); STEP(p3.w);
#undef STEP

    // ---- butterfly combine across the 8-lane group ----
#pragma unroll
    for (int d = 1; d < 8; d <<= 1) {
        const float b0 = __shfl_xor(a0, d);
        const float b1 = __shfl_xor(a1, d);
        const float b2 = __shfl_xor(a2, d);
        const float b3 = __shfl_xor(a3, d);
        const float b4 = __shfl_xor(a4, d);
        const float b5 = __shfl_xor(a5, d);

        float n0 = a0 * b0;
        float n1 = a0 * b1;
        n1 = fmaf(a1, b0, n1);
        float n2 = a0 * b2;
        n2 = fmaf(a1, b1, n2);
        n2 = fmaf(a2, b0, n2);
        float n3 = a0 * b3;
        n3 = fmaf(a1, b2, n3);
        n3 = fmaf(a2, b1, n3);
        n3 = fmaf(a3, b0, n3);
        float n4 = a0 * b4;
        n4 = fmaf(a1, b3, n4);
        n4 = fmaf(a2, b2, n4);
        n4 = fmaf(a3, b1, n4);
        n4 = fmaf(a4, b0, n4);
        // mass conservation: total = (sum a)(sum b) = 1
        const float n5 = 1.0f - (((n0 + n1) + (n2 + n3)) + n4);

        a0 = n0; a1 = n1; a2 = n2; a3 = n3; a4 = n4; a5 = n5;
    }

    // ---- severity + store (lanes m<5 cover 160 contiguous bytes/wave) ----
    if (m < 5) {
        float v;
        switch (m) {
            case 0: v = a0; break;
            case 1: v = a1 + a2; break;
            case 2: v = a3 + a4; break;
            case 3: v = a5; break;
            default: v = 0.0f; break;   // out is re-poisoned: must write zeros
        }
        out[(size_t)row * 5 + m] = v;
    }
}

extern "C" void kernel_launch(void* const* d_in, const int* in_sizes, int n_in,
                              void* d_out, int out_size, void* d_ws, size_t ws_size,
                              hipStream_t stream) {
    const float* x1 = (const float*)d_in[0];
    const float* x2 = (const float*)d_in[1];
    const float* x3 = (const float*)d_in[2];
    float* out = (float*)d_out;

    const int rows = in_sizes[0] / 32;                 // 1048576
    const int blocks = rows / (THREADS / 8);           // 32768 (exact)
    hemorrhage_kernel<<<blocks, THREADS, 0, stream>>>(x1, x2, x3, out);
}